// Round 7
// baseline (1121.658 us; speedup 1.0000x reference)
//
#include <hip/hip_runtime.h>
#include <hip/hip_cooperative_groups.h>

namespace cg = cooperative_groups;

#define N_NODES 50000
#define N_EDGES 600000
#define NBLK    196           // (N_NODES+255)/256
#define KDIM    128
#define APAD    136           // 128 + 8 ushorts pad

typedef short bf16x8 __attribute__((ext_vector_type(8)));
typedef float f32x4  __attribute__((ext_vector_type(4)));
typedef unsigned short u16x8 __attribute__((ext_vector_type(8)));
typedef unsigned short u16x4 __attribute__((ext_vector_type(4)));

// ---------------- bf16 helpers (RNE) ----------------
__device__ inline ushort rne_bf16(float a) {
    union { float f; unsigned u; } v; v.f = a;
    return (ushort)((v.u + 0x7FFFu + ((v.u >> 16) & 1u)) >> 16);
}
__device__ inline float bf16_to_f32(ushort h) {
    return __uint_as_float((unsigned)h << 16);
}
__device__ inline void split_bf16(float a, ushort& hi, ushort& lo) {
    hi = rne_bf16(a);
    float hv = bf16_to_f32(hi);
    lo = rne_bf16(a - hv);
}

// =================== phase device functions ===================
// All use blockIdx/gridDim grid-stride so they run under any grid size.
// Early exits are block- or wave-uniform only; no __syncthreads is skipped
// divergently within a block.

__device__ __forceinline__ void phase_zero(int* __restrict__ degi) {
    const int gtid = blockIdx.x * 256 + threadIdx.x;
    const int gsz = gridDim.x * 256;
    for (int i = gtid; i < N_NODES; i += gsz) degi[i] = 0;
}

__device__ __forceinline__ void phase_count(const int* __restrict__ dst, int* __restrict__ degi) {
    const int gtid = blockIdx.x * 256 + threadIdx.x;
    const int gsz = gridDim.x * 256;
    for (int e = gtid; e < N_EDGES; e += gsz) atomicAdd(&degi[dst[e]], 1);
}

__device__ __forceinline__ void phase_bsum(const int* __restrict__ degi, int* __restrict__ bsum,
                                           int* __restrict__ s) {
    const int t = threadIdx.x;
    for (int w = blockIdx.x; w < NBLK; w += gridDim.x) {
        int i = w * 256 + t;
        s[t] = (i < N_NODES) ? degi[i] : 0;
        __syncthreads();
        #pragma unroll
        for (int d = 128; d > 0; d >>= 1) {
            if (t < d) s[t] += s[t + d];
            __syncthreads();
        }
        if (t == 0) bsum[w] = s[0];
        __syncthreads();
    }
}

__device__ __forceinline__ void phase_scan(const int* __restrict__ degi, const int* __restrict__ bsum,
                                           int* __restrict__ off, int* __restrict__ cur,
                                           int* __restrict__ s) {
    const int t = threadIdx.x;
    for (int w = blockIdx.x; w < NBLK; w += gridDim.x) {
        int bv = (t < NBLK) ? bsum[t] : 0;
        s[t] = bv;
        __syncthreads();
        #pragma unroll
        for (int d = 1; d < 256; d <<= 1) {
            int x = (t >= d) ? s[t - d] : 0;
            __syncthreads();
            s[t] += x;
            __syncthreads();
        }
        int base = (w > 0) ? s[w - 1] : 0;
        if (w == 0 && t == 0) off[N_NODES] = s[255];
        __syncthreads();

        int i = w * 256 + t;
        int v = (i < N_NODES) ? degi[i] : 0;
        s[t] = v;
        __syncthreads();
        #pragma unroll
        for (int d = 1; d < 256; d <<= 1) {
            int x = (t >= d) ? s[t - d] : 0;
            __syncthreads();
            s[t] += x;
            __syncthreads();
        }
        if (i < N_NODES) {
            int excl = s[t] - v + base;
            off[i] = excl;
            cur[i] = excl;
        }
        __syncthreads();
    }
}

__device__ __forceinline__ void phase_fill(const int* __restrict__ src, const int* __restrict__ dst,
                                           int* __restrict__ cur, int* __restrict__ ssrcb) {
    const int gtid = blockIdx.x * 256 + threadIdx.x;
    const int gsz = gridDim.x * 256;
    for (int e = gtid; e < N_EDGES; e += gsz) {
        int p = atomicAdd(&cur[dst[e]], 1);
        ssrcb[p] = src[e];
    }
}

__device__ __forceinline__ void phase_convert(
    const float* __restrict__ ws0, const float* __restrict__ wn0,
    const float* __restrict__ ws1, const float* __restrict__ wn1,
    const float* __restrict__ ws2, const float* __restrict__ wn2,
    ushort* __restrict__ Bth0, ushort* __restrict__ Btl0,
    ushort* __restrict__ Bth1, ushort* __restrict__ Btl1,
    ushort* __restrict__ Bth2, ushort* __restrict__ Btl2) {
    const int gtid = blockIdx.x * 256 + threadIdx.x;
    const int gsz = gridDim.x * 256;
    for (int i = gtid; i < 592 * 128; i += gsz) {
        int bb = i >> 7;
        int k = i & 127;
        const float *Ws, *Wn;
        ushort *H, *L;
        int dout, n;
        if (bb < 256)      { n = bb;       dout = 128; Ws = ws0; Wn = wn0; H = Bth0; L = Btl0; }
        else if (bb < 512) { n = bb - 256; dout = 128; Ws = ws1; Wn = wn1; H = Bth1; L = Btl1; }
        else               { n = bb - 512; dout = 40;  Ws = ws2; Wn = wn2; H = Bth2; L = Btl2; }
        float w = (n < dout) ? Ws[(long)k * dout + n] : Wn[(long)k * dout + (n - dout)];
        ushort hi, lo;
        split_bf16(w, hi, lo);
        H[n * 128 + k] = hi;
        L[n * 128 + k] = lo;
    }
}

// ---- GEMM staging helpers ----
__device__ __forceinline__ void load_a16(const float* __restrict__ A, int grow, int M, int seg,
                                         float* __restrict__ f) {
    if (grow < M) {
        const float* ap = A + (long)grow * KDIM + seg;
        #pragma unroll
        for (int q = 0; q < 4; ++q) {
            float4 a = *(const float4*)(ap + q * 4);
            f[q * 4 + 0] = a.x; f[q * 4 + 1] = a.y;
            f[q * 4 + 2] = a.z; f[q * 4 + 3] = a.w;
        }
    } else {
        #pragma unroll
        for (int i = 0; i < 16; ++i) f[i] = 0.f;
    }
}

__device__ __forceinline__ void split_store16(const float* __restrict__ f,
                                              ushort* __restrict__ Ahi, ushort* __restrict__ Alo,
                                              int m, int seg) {
    ushort h[16], l[16];
    #pragma unroll
    for (int i = 0; i < 16; ++i) split_bf16(f[i], h[i], l[i]);
    #pragma unroll
    for (int q = 0; q < 2; ++q) {
        uint4 hw, lw;
        hw.x = (unsigned)h[q*8+0] | ((unsigned)h[q*8+1] << 16);
        hw.y = (unsigned)h[q*8+2] | ((unsigned)h[q*8+3] << 16);
        hw.z = (unsigned)h[q*8+4] | ((unsigned)h[q*8+5] << 16);
        hw.w = (unsigned)h[q*8+6] | ((unsigned)h[q*8+7] << 16);
        lw.x = (unsigned)l[q*8+0] | ((unsigned)l[q*8+1] << 16);
        lw.y = (unsigned)l[q*8+2] | ((unsigned)l[q*8+3] << 16);
        lw.z = (unsigned)l[q*8+4] | ((unsigned)l[q*8+5] << 16);
        lw.w = (unsigned)l[q*8+6] | ((unsigned)l[q*8+7] << 16);
        *(uint4*)&Ahi[m * APAD + seg + q * 8] = hw;
        *(uint4*)&Alo[m * APAD + seg + q * 8] = lw;
    }
}

// ---- wide GEMM phase (r6 structure: persistent B regs, dbuf LDS, prefetch) ----
__device__ __forceinline__ void gemm_wide_phase(
    const float* __restrict__ A,
    const ushort* __restrict__ Bth, const ushort* __restrict__ Btl,
    const float* __restrict__ bias,
    float* __restrict__ S, ushort* __restrict__ T, char* ldsraw, int M)
{
    ushort* AhiB = (ushort*)ldsraw;             // [2][32*APAD]
    ushort* AloB = (ushort*)(ldsraw + 17408);   // [2][32*APAD]

    const int tid = threadIdx.x;
    const int wave = tid >> 6;
    const int lane = tid & 63;
    const int lane16 = lane & 15;
    const int quad = lane >> 4;
    const int half = blockIdx.x & 1;              // 0 -> S, 1 -> T
    const int colbase = half * 128 + wave * 32;
    const int ntiles = (M + 31) >> 5;
    const int bstride = gridDim.x >> 1;
    const int m   = tid >> 3;
    const int seg = (tid & 7) * 16;

    bf16x8 Bh[4][2], Bl[4][2];
    #pragma unroll
    for (int c = 0; c < 4; ++c) {
        #pragma unroll
        for (int ct = 0; ct < 2; ++ct) {
            const long boff = (long)(colbase + 16 * ct + lane16) * KDIM + c * 32 + quad * 8;
            Bh[c][ct] = *(const bf16x8*)(Bth + boff);
            Bl[c][ct] = *(const bf16x8*)(Btl + boff);
        }
    }
    f32x4 bv[2] = {};
    if (half == 0) {
        #pragma unroll
        for (int ct = 0; ct < 2; ++ct)
            bv[ct] = *(const f32x4*)(bias + wave * 32 + 16 * ct + quad * 4);
    }

    int rt = blockIdx.x >> 1;
    if (rt >= ntiles) return;   // block-uniform

    float fa[16];
    load_a16(A, rt * 32 + m, M, seg, fa);
    split_store16(fa, AhiB, AloB, m, seg);
    __syncthreads();

    int cur = 0;
    while (true) {
        const int nrt = rt + bstride;
        float fn[16];
        if (nrt < ntiles) load_a16(A, nrt * 32 + m, M, seg, fn);

        const ushort* AH = AhiB + cur * 4352;
        const ushort* AL = AloB + cur * 4352;

        f32x4 acc[2][2] = {};
        #pragma unroll
        for (int c = 0; c < 4; ++c) {
            const int k0 = c * 32 + quad * 8;
            bf16x8 ah[2], al[2];
            #pragma unroll
            for (int r = 0; r < 2; ++r) {
                const int off = (16 * r + lane16) * APAD + k0;
                ah[r] = *(const bf16x8*)&AH[off];
                al[r] = *(const bf16x8*)&AL[off];
            }
            #pragma unroll
            for (int ct = 0; ct < 2; ++ct) {
                #pragma unroll
                for (int r = 0; r < 2; ++r) {
                    acc[r][ct] = __builtin_amdgcn_mfma_f32_16x16x32_bf16(Bh[c][ct], ah[r], acc[r][ct], 0, 0, 0);
                    acc[r][ct] = __builtin_amdgcn_mfma_f32_16x16x32_bf16(Bl[c][ct], ah[r], acc[r][ct], 0, 0, 0);
                    acc[r][ct] = __builtin_amdgcn_mfma_f32_16x16x32_bf16(Bh[c][ct], al[r], acc[r][ct], 0, 0, 0);
                }
            }
        }

        #pragma unroll
        for (int ct = 0; ct < 2; ++ct) {
            const int colL = wave * 32 + 16 * ct + quad * 4;
            #pragma unroll
            for (int r = 0; r < 2; ++r) {
                const int row = rt * 32 + 16 * r + lane16;
                if (row < M) {
                    if (half == 0) {
                        *(f32x4*)(S + (long)row * 128 + colL) = acc[r][ct] + bv[ct];
                    } else {
                        u16x4 t4;
                        #pragma unroll
                        for (int i = 0; i < 4; ++i) t4[i] = rne_bf16(acc[r][ct][i]);
                        *(u16x4*)(T + (long)row * 128 + colL) = t4;
                    }
                }
            }
        }

        if (nrt >= ntiles) break;
        split_store16(fn, AhiB + (cur ^ 1) * 4352, AloB + (cur ^ 1) * 4352, m, seg);
        __syncthreads();
        cur ^= 1;
        rt = nrt;
    }
}

// ---- narrow GEMM phase (r6 structure) ----
__device__ __forceinline__ void gemm_narrow_phase(
    const float* __restrict__ A,
    const ushort* __restrict__ Bth, const ushort* __restrict__ Btl,
    const float* __restrict__ bias,
    float* __restrict__ S, ushort* __restrict__ T, char* ldsraw, int M)
{
    ushort* AhiB = (ushort*)ldsraw;
    ushort* AloB = (ushort*)(ldsraw + 17408);

    const int tid = threadIdx.x;
    const int wave = tid >> 6;
    const int lane = tid & 63;
    const int lane16 = lane & 15;
    const int quad = lane >> 4;
    const int rtw = wave & 1;
    const int cg = wave >> 1;
    const int ctbase = cg * 3;
    const int nct = cg ? 2 : 3;
    const int ntiles = (M + 31) >> 5;
    const int m   = tid >> 3;
    const int seg = (tid & 7) * 16;

    bf16x8 Bh[4][3], Bl[4][3];
    #pragma unroll
    for (int c = 0; c < 4; ++c) {
        #pragma unroll
        for (int j = 0; j < 3; ++j) {
            if (j < nct) {
                const long boff = (long)(16 * (ctbase + j) + lane16) * KDIM + c * 32 + quad * 8;
                Bh[c][j] = *(const bf16x8*)(Bth + boff);
                Bl[c][j] = *(const bf16x8*)(Btl + boff);
            }
        }
    }

    int rt = blockIdx.x;
    if (rt >= ntiles) return;   // block-uniform

    float fa[16];
    load_a16(A, rt * 32 + m, M, seg, fa);
    split_store16(fa, AhiB, AloB, m, seg);
    __syncthreads();

    int cur = 0;
    while (true) {
        const int nrt = rt + gridDim.x;
        float fn[16];
        if (nrt < ntiles) load_a16(A, nrt * 32 + m, M, seg, fn);

        const ushort* AH = AhiB + cur * 4352;
        const ushort* AL = AloB + cur * 4352;

        f32x4 acc[3] = {};
        #pragma unroll
        for (int c = 0; c < 4; ++c) {
            const int off = (rtw * 16 + lane16) * APAD + c * 32 + quad * 8;
            bf16x8 ah = *(const bf16x8*)&AH[off];
            bf16x8 al = *(const bf16x8*)&AL[off];
            #pragma unroll
            for (int j = 0; j < 3; ++j) {
                if (j < nct) {
                    acc[j] = __builtin_amdgcn_mfma_f32_16x16x32_bf16(Bh[c][j], ah, acc[j], 0, 0, 0);
                    acc[j] = __builtin_amdgcn_mfma_f32_16x16x32_bf16(Bl[c][j], ah, acc[j], 0, 0, 0);
                    acc[j] = __builtin_amdgcn_mfma_f32_16x16x32_bf16(Bh[c][j], al, acc[j], 0, 0, 0);
                }
            }
        }

        const int row = rt * 32 + rtw * 16 + lane16;
        #pragma unroll
        for (int j = 0; j < 3; ++j) {
            if (j < nct && row < M) {
                const int col0 = 16 * (ctbase + j) + quad * 4;
                if (col0 < 40) {
                    f32x4 bvv = *(const f32x4*)(bias + col0);
                    *(f32x4*)(S + (long)row * 40 + col0) = acc[j] + bvv;
                } else {
                    u16x4 t4;
                    #pragma unroll
                    for (int i = 0; i < 4; ++i) t4[i] = rne_bf16(acc[j][i]);
                    *(u16x4*)(T + (long)row * 40 + (col0 - 40)) = t4;
                }
            }
        }

        if (nrt >= ntiles) break;
        split_store16(fn, AhiB + (cur ^ 1) * 4352, AloB + (cur ^ 1) * 4352, m, seg);
        __syncthreads();
        cur ^= 1;
        rt = nrt;
    }
}

// ---- aggregation phases ----
template <int RELU>
__device__ __forceinline__ void agg128_phase(
    const float* __restrict__ S, const ushort* __restrict__ T,
    const int* __restrict__ off, const int* __restrict__ ssrcb,
    float* __restrict__ out)
{
    const int wave = threadIdx.x >> 6;
    const int lane = threadIdx.x & 63;
    const int slot = lane >> 4;
    const int col8 = (lane & 15) * 8;
    const int ngroups = (N_NODES + 3) >> 2;

    for (int g = blockIdx.x; g < ngroups; g += gridDim.x) {
        const int node = g * 4 + wave;
        if (node >= N_NODES) continue;   // wave-uniform

        const int a = off[node];
        const int b = off[node + 1];

        f32x4 acc0a = {0,0,0,0}, acc0b = {0,0,0,0};
        f32x4 acc1a = {0,0,0,0}, acc1b = {0,0,0,0};

        int i = a;
        for (; i + 8 <= b; i += 8) {
            int s0 = ssrcb[i + slot];
            int s1 = ssrcb[i + 4 + slot];
            u16x8 v0 = *(const u16x8*)(T + (long)s0 * 128 + col8);
            u16x8 v1 = *(const u16x8*)(T + (long)s1 * 128 + col8);
            #pragma unroll
            for (int j = 0; j < 4; ++j) {
                acc0a[j] += bf16_to_f32(v0[j]);
                acc0b[j] += bf16_to_f32(v0[4 + j]);
                acc1a[j] += bf16_to_f32(v1[j]);
                acc1b[j] += bf16_to_f32(v1[4 + j]);
            }
        }
        for (; i < b; i += 4) {
            int e = i + slot;
            if (e < b) {
                int s = ssrcb[e];
                u16x8 v = *(const u16x8*)(T + (long)s * 128 + col8);
                #pragma unroll
                for (int j = 0; j < 4; ++j) {
                    acc0a[j] += bf16_to_f32(v[j]);
                    acc0b[j] += bf16_to_f32(v[4 + j]);
                }
            }
        }
        f32x4 accA = acc0a + acc1a;
        f32x4 accB = acc0b + acc1b;

        #pragma unroll
        for (int mm = 16; mm <= 32; mm <<= 1) {
            #pragma unroll
            for (int j = 0; j < 4; ++j) {
                accA[j] += __shfl_xor((float)accA[j], mm);
                accB[j] += __shfl_xor((float)accB[j], mm);
            }
        }

        if (slot == 0) {
            int deg = b - a;
            float scale = (deg > 0) ? (1.0f / (float)deg) : 0.f;
            f32x4 sA = *(const f32x4*)(S + (long)node * 128 + col8);
            f32x4 sB = *(const f32x4*)(S + (long)node * 128 + col8 + 4);
            f32x4 rA = sA + accA * scale;
            f32x4 rB = sB + accB * scale;
            if (RELU) {
                #pragma unroll
                for (int j = 0; j < 4; ++j) {
                    rA[j] = fmaxf(rA[j], 0.f);
                    rB[j] = fmaxf(rB[j], 0.f);
                }
            }
            *(f32x4*)(out + (long)node * 128 + col8) = rA;
            *(f32x4*)(out + (long)node * 128 + col8 + 4) = rB;
        }
    }
}

template <int RELU>
__device__ __forceinline__ void agg40_phase(
    const float* __restrict__ S, const ushort* __restrict__ T,
    const int* __restrict__ off, const int* __restrict__ ssrcb,
    float* __restrict__ out)
{
    const int wave = threadIdx.x >> 6;
    const int lane = threadIdx.x & 63;
    const bool active = lane < 60;
    const int slot = active ? (lane / 10) : 5;
    const int fi = lane % 10;
    const int fo = fi * 4;
    const int ngroups = (N_NODES + 3) >> 2;

    for (int g = blockIdx.x; g < ngroups; g += gridDim.x) {
        const int node = g * 4 + wave;
        if (node >= N_NODES) continue;   // wave-uniform

        const int a = off[node];
        const int b = off[node + 1];

        f32x4 acc0 = {0,0,0,0}, acc1 = {0,0,0,0};

        int i = a;
        for (; i + 12 <= b; i += 12) {
            int s0 = ssrcb[i + slot];
            int s1 = ssrcb[i + 6 + slot];
            u16x4 v0 = *(const u16x4*)(T + (long)s0 * 40 + fo);
            u16x4 v1 = *(const u16x4*)(T + (long)s1 * 40 + fo);
            if (active) {
                #pragma unroll
                for (int j = 0; j < 4; ++j) {
                    acc0[j] += bf16_to_f32(v0[j]);
                    acc1[j] += bf16_to_f32(v1[j]);
                }
            }
        }
        for (; i < b; i += 6) {
            int e = i + slot;
            if (active && e < b) {
                int s = ssrcb[e];
                u16x4 v = *(const u16x4*)(T + (long)s * 40 + fo);
                #pragma unroll
                for (int j = 0; j < 4; ++j) acc0[j] += bf16_to_f32(v[j]);
            }
        }
        f32x4 acc = acc0 + acc1;

        f32x4 tot = acc;
        #pragma unroll
        for (int d = 10; d <= 50; d += 10) {
            int srcl = fi + d;
            #pragma unroll
            for (int j = 0; j < 4; ++j) tot[j] += __shfl((float)acc[j], srcl);
        }

        if (lane < 10) {
            int deg = b - a;
            float scale = (deg > 0) ? (1.0f / (float)deg) : 0.f;
            f32x4 s4 = *(const f32x4*)(S + (long)node * 40 + fo);
            f32x4 r = s4 + tot * scale;
            if (RELU) {
                #pragma unroll
                for (int j = 0; j < 4; ++j) r[j] = fmaxf(r[j], 0.f);
            }
            *(f32x4*)(out + (long)node * 40 + fo) = r;
        }
    }
}

// =================== cooperative mega-kernel ===================

__global__ __launch_bounds__(256, 3) void mega(
    const float* feat, const int* src, const int* dst,
    const float* ws0, const float* wn0, const float* b0,
    const float* ws1, const float* wn1, const float* b1,
    const float* ws2, const float* wn2, const float* b2,
    int* offsets, int* cursor, int* degi, int* bsum, int* ssrcb,
    ushort* Bth0, ushort* Btl0, ushort* Bth1, ushort* Btl1, ushort* Bth2, ushort* Btl2,
    float* hbuf, float* sbuf, ushort* tbuf, float* outp)
{
    cg::grid_group grid = cg::this_grid();
    __shared__ __align__(16) char lds[34816];
    int* si = (int*)lds;

    // ---- CSR build (B buffers overlap cursor/degi; convert runs after) ----
    phase_zero(degi);
    __threadfence(); grid.sync();
    phase_count(dst, degi);
    __threadfence(); grid.sync();
    phase_bsum(degi, bsum, si);
    __threadfence(); grid.sync();
    phase_scan(degi, bsum, offsets, cursor, si);
    __threadfence(); grid.sync();
    phase_fill(src, dst, cursor, ssrcb);
    __threadfence(); grid.sync();

    // ---- weight convert (cursor/degi now dead) ----
    phase_convert(ws0, wn0, ws1, wn1, ws2, wn2, Bth0, Btl0, Bth1, Btl1, Bth2, Btl2);
    __threadfence(); grid.sync();

    // ---- layer 0 ----
    gemm_wide_phase(feat, Bth0, Btl0, b0, sbuf, tbuf, lds, N_NODES);
    __threadfence(); grid.sync();
    agg128_phase<1>(sbuf, tbuf, offsets, ssrcb, hbuf);
    __threadfence(); grid.sync();

    // ---- layer 1 ----
    gemm_wide_phase(hbuf, Bth1, Btl1, b1, sbuf, tbuf, lds, N_NODES);
    __threadfence(); grid.sync();
    agg128_phase<1>(sbuf, tbuf, offsets, ssrcb, hbuf);
    __threadfence(); grid.sync();

    // ---- layer 2 ----
    gemm_narrow_phase(hbuf, Bth2, Btl2, b2, sbuf, tbuf, lds, N_NODES);
    __threadfence(); grid.sync();
    agg40_phase<0>(sbuf, tbuf, offsets, ssrcb, outp);
}

// =================== fallback wrappers (non-cooperative path) ===================

__global__ __launch_bounds__(256) void k_zero(int* degi) { phase_zero(degi); }
__global__ __launch_bounds__(256) void k_count(const int* dst, int* degi) { phase_count(dst, degi); }
__global__ __launch_bounds__(256) void k_bsum(const int* degi, int* bsum) {
    __shared__ int s[256];
    phase_bsum(degi, bsum, s);
}
__global__ __launch_bounds__(256) void k_scan(const int* degi, const int* bsum, int* off, int* cur) {
    __shared__ int s[256];
    phase_scan(degi, bsum, off, cur, s);
}
__global__ __launch_bounds__(256) void k_fill(const int* src, const int* dst, int* cur, int* ssrcb) {
    phase_fill(src, dst, cur, ssrcb);
}
__global__ __launch_bounds__(256) void k_convert(
    const float* ws0, const float* wn0, const float* ws1, const float* wn1,
    const float* ws2, const float* wn2,
    ushort* Bth0, ushort* Btl0, ushort* Bth1, ushort* Btl1, ushort* Bth2, ushort* Btl2) {
    phase_convert(ws0, wn0, ws1, wn1, ws2, wn2, Bth0, Btl0, Bth1, Btl1, Bth2, Btl2);
}
__global__ __launch_bounds__(256, 3) void k_gemm_wide(
    const float* A, const ushort* Bth, const ushort* Btl, const float* bias,
    float* S, ushort* T, int M) {
    __shared__ __align__(16) char lds[34816];
    gemm_wide_phase(A, Bth, Btl, bias, S, T, lds, M);
}
__global__ __launch_bounds__(256, 2) void k_gemm_narrow(
    const float* A, const ushort* Bth, const ushort* Btl, const float* bias,
    float* S, ushort* T, int M) {
    __shared__ __align__(16) char lds[34816];
    gemm_narrow_phase(A, Bth, Btl, bias, S, T, lds, M);
}
template <int RELU>
__global__ __launch_bounds__(256) void k_agg128(
    const float* S, const ushort* T, const int* off, const int* ssrcb, float* out) {
    agg128_phase<RELU>(S, T, off, ssrcb, out);
}
template <int RELU>
__global__ __launch_bounds__(256) void k_agg40(
    const float* S, const ushort* T, const int* off, const int* ssrcb, float* out) {
    agg40_phase<RELU>(S, T, off, ssrcb, out);
}

// =================== launch ===================

extern "C" void kernel_launch(void* const* d_in, const int* in_sizes, int n_in,
                              void* d_out, int out_size, void* d_ws, size_t ws_size,
                              hipStream_t stream) {
    const float* feat = (const float*)d_in[0];
    const int*   src  = (const int*)d_in[1];
    const int*   dst  = (const int*)d_in[2];
    const float* ws0  = (const float*)d_in[3];
    const float* wn0  = (const float*)d_in[4];
    const float* b0   = (const float*)d_in[5];
    const float* ws1  = (const float*)d_in[6];
    const float* wn1  = (const float*)d_in[7];
    const float* b1   = (const float*)d_in[8];
    const float* ws2  = (const float*)d_in[9];
    const float* wn2  = (const float*)d_in[10];
    const float* b2   = (const float*)d_in[11];

    char* ws = (char*)d_ws;
    int*    offsets = (int*)(ws + 0);
    int*    cursor  = (int*)(ws + 200704);
    int*    degi    = (int*)(ws + 401408);
    int*    bsum    = (int*)(ws + 601600);
    int*    ssrcb   = (int*)(ws + 603648);
    ushort* Bth0 = (ushort*)(ws + 200704);   // overlap cursor/degi; convert runs after CSR
    ushort* Btl0 = (ushort*)(ws + 266240);
    ushort* Bth1 = (ushort*)(ws + 331776);
    ushort* Btl1 = (ushort*)(ws + 397312);
    ushort* Bth2 = (ushort*)(ws + 462848);
    ushort* Btl2 = (ushort*)(ws + 483328);
    float*  hbuf = (float*)(ws + 3003904);   // 25.6 MB fp32
    float*  sbuf = (float*)(ws + 28603904);  // 25.6 MB fp32
    ushort* tbuf = (ushort*)(ws + 54203904); // 12.8 MB bf16
    float*  outp = (float*)d_out;

    // ---- cooperative mega-kernel (grid sized to co-residency) ----
    int maxb = 0;
    hipError_t qerr = hipOccupancyMaxActiveBlocksPerMultiprocessor(&maxb, mega, 256, 0);
    if (qerr != hipSuccess || maxb < 1) maxb = 2;
    int grid = maxb * 256;           // 256 CUs on MI355X
    if (grid > 1024) grid = 1024;
    grid &= ~1;                      // wide GEMM needs an even grid
    if (grid < 2) grid = 2;

    void* args[] = {
        (void*)&feat, (void*)&src, (void*)&dst,
        (void*)&ws0, (void*)&wn0, (void*)&b0,
        (void*)&ws1, (void*)&wn1, (void*)&b1,
        (void*)&ws2, (void*)&wn2, (void*)&b2,
        (void*)&offsets, (void*)&cursor, (void*)&degi, (void*)&bsum, (void*)&ssrcb,
        (void*)&Bth0, (void*)&Btl0, (void*)&Bth1, (void*)&Btl1, (void*)&Bth2, (void*)&Btl2,
        (void*)&hbuf, (void*)&sbuf, (void*)&tbuf, (void*)&outp
    };

    hipError_t err = hipLaunchCooperativeKernel(mega, dim3(grid), dim3(256), args, 0, stream);

    if (err != hipSuccess) {
        // ---- fallback: per-kernel sequence (round-6 structure) ----
        k_zero<<<768, 256, 0, stream>>>(degi);
        k_count<<<768, 256, 0, stream>>>(dst, degi);
        k_bsum<<<NBLK, 256, 0, stream>>>(degi, bsum);
        k_scan<<<NBLK, 256, 0, stream>>>(degi, bsum, offsets, cursor);
        k_fill<<<768, 256, 0, stream>>>(src, dst, cursor, ssrcb);
        k_convert<<<592, 256, 0, stream>>>(ws0, wn0, ws1, wn1, ws2, wn2,
                                           Bth0, Btl0, Bth1, Btl1, Bth2, Btl2);
        k_gemm_wide<<<768, 256, 0, stream>>>(feat, Bth0, Btl0, b0, sbuf, tbuf, N_NODES);
        k_agg128<1><<<768, 256, 0, stream>>>(sbuf, tbuf, offsets, ssrcb, hbuf);
        k_gemm_wide<<<768, 256, 0, stream>>>(hbuf, Bth1, Btl1, b1, sbuf, tbuf, N_NODES);
        k_agg128<1><<<768, 256, 0, stream>>>(sbuf, tbuf, offsets, ssrcb, hbuf);
        k_gemm_narrow<<<512, 256, 0, stream>>>(hbuf, Bth2, Btl2, b2, sbuf, tbuf, N_NODES);
        k_agg40<0><<<768, 256, 0, stream>>>(sbuf, tbuf, offsets, ssrcb, outp);
    }
}

// Round 8
// 275.894 us; speedup vs baseline: 4.0655x; 4.0655x over previous
//
#include <hip/hip_runtime.h>

#define N_NODES 50000
#define N_EDGES 600000
#define NBLK    196           // (N_NODES+255)/256
#define KDIM    128
#define APAD    136           // 128 + 8 ushorts pad (272B row stride -> 2-way banks, free)

typedef short bf16x8 __attribute__((ext_vector_type(8)));
typedef float f32x4  __attribute__((ext_vector_type(4)));
typedef unsigned short u16x8 __attribute__((ext_vector_type(8)));
typedef unsigned short u16x4 __attribute__((ext_vector_type(4)));

// ---------------- bf16 helpers (RNE) ----------------
__device__ inline ushort rne_bf16(float a) {
    union { float f; unsigned u; } v; v.f = a;
    return (ushort)((v.u + 0x7FFFu + ((v.u >> 16) & 1u)) >> 16);
}
__device__ inline float bf16_to_f32(ushort h) {
    return __uint_as_float((unsigned)h << 16);
}
__device__ inline void split_bf16(float a, ushort& hi, ushort& lo) {
    hi = rne_bf16(a);
    float hv = bf16_to_f32(hi);
    lo = rne_bf16(a - hv);
}

// =============== K1: fused count_deg || convert_w (independent work) ===============
__global__ __launch_bounds__(256) void k_prep(
    const int* __restrict__ dst, int* __restrict__ degi,
    const float* __restrict__ ws0, const float* __restrict__ wn0,
    const float* __restrict__ ws1, const float* __restrict__ wn1,
    const float* __restrict__ ws2, const float* __restrict__ wn2,
    ushort* __restrict__ Bth0, ushort* __restrict__ Btl0,
    ushort* __restrict__ Bth1, ushort* __restrict__ Btl1,
    ushort* __restrict__ Bth2, ushort* __restrict__ Btl2)
{
    const int b = blockIdx.x, t = threadIdx.x;
    if (b < 192) {
        for (int e = b * 256 + t; e < N_EDGES; e += 192 * 256)
            atomicAdd(&degi[dst[e]], 1);
    } else {
        for (int i = (b - 192) * 256 + t; i < 592 * 128; i += 64 * 256) {
            int bb = i >> 7, k = i & 127;
            const float *Ws, *Wn;
            ushort *H, *L;
            int dout, n;
            if (bb < 256)      { n = bb;       dout = 128; Ws = ws0; Wn = wn0; H = Bth0; L = Btl0; }
            else if (bb < 512) { n = bb - 256; dout = 128; Ws = ws1; Wn = wn1; H = Bth1; L = Btl1; }
            else               { n = bb - 512; dout = 40;  Ws = ws2; Wn = wn2; H = Bth2; L = Btl2; }
            float w = (n < dout) ? Ws[(long)k * dout + n] : Wn[(long)k * dout + (n - dout)];
            ushort hi, lo;
            split_bf16(w, hi, lo);
            H[n * 128 + k] = hi;
            L[n * 128 + k] = lo;
        }
    }
}

// =============== CSR scan kernels (unchanged, r3-r6) ===============
__global__ __launch_bounds__(256) void block_sums_kernel(const int* __restrict__ deg,
                                                         int* __restrict__ bsum, int n) {
    __shared__ int s[256];
    int t = threadIdx.x;
    int i = blockIdx.x * 256 + t;
    s[t] = (i < n) ? deg[i] : 0;
    __syncthreads();
    #pragma unroll
    for (int d = 128; d > 0; d >>= 1) {
        if (t < d) s[t] += s[t + d];
        __syncthreads();
    }
    if (t == 0) bsum[blockIdx.x] = s[0];
}

__global__ __launch_bounds__(256) void scatter_fused_kernel(const int* __restrict__ deg,
                                                            const int* __restrict__ bsum,
                                                            int* __restrict__ off,
                                                            int* __restrict__ cur,
                                                            int n, int nb) {
    __shared__ int s[256];
    int t = threadIdx.x;

    int bv = (t < nb) ? bsum[t] : 0;
    s[t] = bv;
    __syncthreads();
    #pragma unroll
    for (int d = 1; d < 256; d <<= 1) {
        int x = (t >= d) ? s[t - d] : 0;
        __syncthreads();
        s[t] += x;
        __syncthreads();
    }
    int base = (blockIdx.x > 0) ? s[blockIdx.x - 1] : 0;
    if (blockIdx.x == 0 && t == 0) off[n] = s[255];
    __syncthreads();

    int i = blockIdx.x * 256 + t;
    int v = (i < n) ? deg[i] : 0;
    s[t] = v;
    __syncthreads();
    #pragma unroll
    for (int d = 1; d < 256; d <<= 1) {
        int x = (t >= d) ? s[t - d] : 0;
        __syncthreads();
        s[t] += x;
        __syncthreads();
    }
    if (i < n) {
        int excl = s[t] - v + base;
        off[i] = excl;
        cur[i] = excl;
    }
}

// =============== GEMM staging helpers ===============
__device__ __forceinline__ void load_a16(const float* __restrict__ A, int grow, int M, int seg,
                                         float* __restrict__ f) {
    if (grow < M) {
        const float* ap = A + (long)grow * KDIM + seg;
        #pragma unroll
        for (int q = 0; q < 4; ++q) {
            float4 a = *(const float4*)(ap + q * 4);
            f[q * 4 + 0] = a.x; f[q * 4 + 1] = a.y;
            f[q * 4 + 2] = a.z; f[q * 4 + 3] = a.w;
        }
    } else {
        #pragma unroll
        for (int i = 0; i < 16; ++i) f[i] = 0.f;
    }
}

__device__ __forceinline__ void split_store16(const float* __restrict__ f,
                                              ushort* __restrict__ Ahi, ushort* __restrict__ Alo,
                                              int m, int seg) {
    ushort h[16], l[16];
    #pragma unroll
    for (int i = 0; i < 16; ++i) split_bf16(f[i], h[i], l[i]);
    #pragma unroll
    for (int q = 0; q < 2; ++q) {
        uint4 hw, lw;
        hw.x = (unsigned)h[q*8+0] | ((unsigned)h[q*8+1] << 16);
        hw.y = (unsigned)h[q*8+2] | ((unsigned)h[q*8+3] << 16);
        hw.z = (unsigned)h[q*8+4] | ((unsigned)h[q*8+5] << 16);
        hw.w = (unsigned)h[q*8+6] | ((unsigned)h[q*8+7] << 16);
        lw.x = (unsigned)l[q*8+0] | ((unsigned)l[q*8+1] << 16);
        lw.y = (unsigned)l[q*8+2] | ((unsigned)l[q*8+3] << 16);
        lw.z = (unsigned)l[q*8+4] | ((unsigned)l[q*8+5] << 16);
        lw.w = (unsigned)l[q*8+6] | ((unsigned)l[q*8+7] << 16);
        *(uint4*)&Ahi[m * APAD + seg + q * 8] = hw;
        *(uint4*)&Alo[m * APAD + seg + q * 8] = lw;
    }
}

// plane staging: pure copy (split was precomputed by agg / convert)
__device__ __forceinline__ void load_pl(const ushort* __restrict__ Phi, const ushort* __restrict__ Plo,
                                        int grow, int M, int seg, uint4* __restrict__ r) {
    if (grow < M) {
        const uint4* ph = (const uint4*)(Phi + (long)grow * KDIM + seg);
        const uint4* pl = (const uint4*)(Plo + (long)grow * KDIM + seg);
        r[0] = ph[0]; r[1] = ph[1];
        r[2] = pl[0]; r[3] = pl[1];
    } else {
        uint4 z = {0, 0, 0, 0};
        r[0] = r[1] = r[2] = r[3] = z;
    }
}

__device__ __forceinline__ void store_pl(const uint4* __restrict__ r,
                                         ushort* __restrict__ Ahi, ushort* __restrict__ Alo,
                                         int m, int seg) {
    *(uint4*)&Ahi[m * APAD + seg] = r[0];
    *(uint4*)&Ahi[m * APAD + seg + 8] = r[1];
    *(uint4*)&Alo[m * APAD + seg] = r[2];
    *(uint4*)&Alo[m * APAD + seg + 8] = r[3];
}

// =============== wide GEMM core (B in regs, dbuf LDS, prefetch) ===============
// half: 0 -> S cols 0-127 (+bias), 1 -> T cols 128-255 (bf16)
#define WIDE_MFMA_TILE()                                                                      \
    f32x4 acc[2][2] = {};                                                                     \
    _Pragma("unroll")                                                                         \
    for (int c = 0; c < 4; ++c) {                                                             \
        const int k0 = c * 32 + quad * 8;                                                     \
        bf16x8 ah[2], al[2];                                                                  \
        _Pragma("unroll")                                                                     \
        for (int r = 0; r < 2; ++r) {                                                         \
            const int off = (16 * r + lane16) * APAD + k0;                                    \
            ah[r] = *(const bf16x8*)&AH[off];                                                 \
            al[r] = *(const bf16x8*)&AL[off];                                                 \
        }                                                                                     \
        _Pragma("unroll")                                                                     \
        for (int ct = 0; ct < 2; ++ct) {                                                      \
            _Pragma("unroll")                                                                 \
            for (int r = 0; r < 2; ++r) {                                                     \
                acc[r][ct] = __builtin_amdgcn_mfma_f32_16x16x32_bf16(Bh[c][ct], ah[r], acc[r][ct], 0, 0, 0); \
                acc[r][ct] = __builtin_amdgcn_mfma_f32_16x16x32_bf16(Bl[c][ct], ah[r], acc[r][ct], 0, 0, 0); \
                acc[r][ct] = __builtin_amdgcn_mfma_f32_16x16x32_bf16(Bh[c][ct], al[r], acc[r][ct], 0, 0, 0); \
            }                                                                                 \
        }                                                                                     \
    }

#define WIDE_STORE_TILE()                                                                     \
    _Pragma("unroll")                                                                         \
    for (int ct = 0; ct < 2; ++ct) {                                                          \
        const int colL = wave * 32 + 16 * ct + quad * 4;                                      \
        _Pragma("unroll")                                                                     \
        for (int r = 0; r < 2; ++r) {                                                         \
            const int row = rt * 32 + 16 * r + lane16;                                        \
            if (row < M) {                                                                    \
                if (half == 0) {                                                              \
                    *(f32x4*)(S + (long)row * 128 + colL) = acc[r][ct] + bv[ct];              \
                } else {                                                                      \
                    u16x4 t4;                                                                 \
                    _Pragma("unroll")                                                         \
                    for (int i = 0; i < 4; ++i) t4[i] = rne_bf16(acc[r][ct][i]);              \
                    *(u16x4*)(T + (long)row * 128 + colL) = t4;                               \
                }                                                                             \
            }                                                                                 \
        }                                                                                     \
    }

#define WIDE_B_PROLOGUE()                                                                     \
    bf16x8 Bh[4][2], Bl[4][2];                                                                \
    _Pragma("unroll")                                                                         \
    for (int c = 0; c < 4; ++c) {                                                             \
        _Pragma("unroll")                                                                     \
        for (int ct = 0; ct < 2; ++ct) {                                                      \
            const long boff = (long)(colbase + 16 * ct + lane16) * KDIM + c * 32 + quad * 8;  \
            Bh[c][ct] = *(const bf16x8*)(Bth + boff);                                         \
            Bl[c][ct] = *(const bf16x8*)(Btl + boff);                                         \
        }                                                                                     \
    }                                                                                         \
    f32x4 bv[2] = {};                                                                         \
    if (half == 0) {                                                                          \
        _Pragma("unroll")                                                                     \
        for (int ct = 0; ct < 2; ++ct)                                                        \
            bv[ct] = *(const f32x4*)(bias + wave * 32 + 16 * ct + quad * 4);                  \
    }

// ---- L0: fp32 A (in-kernel split) + fill_csr riding in blocks [0,128) ----
__global__ __launch_bounds__(256, 3) void k_gemm_wide_f32_fill(
    const float* __restrict__ A,
    const ushort* __restrict__ Bth, const ushort* __restrict__ Btl,
    const float* __restrict__ bias,
    float* __restrict__ S, ushort* __restrict__ T, int M,
    const int* __restrict__ src, const int* __restrict__ dst,
    int* __restrict__ cur, int* __restrict__ ssrcb)
{
    __shared__ ushort AhiB[2][32 * APAD];
    __shared__ ushort AloB[2][32 * APAD];

    if (blockIdx.x < 128) {   // fill_csr (starts at t=0, hidden under GEMM)
        const int gtid = blockIdx.x * 256 + threadIdx.x;
        for (int e = gtid; e < N_EDGES; e += 128 * 256) {
            int p = atomicAdd(&cur[dst[e]], 1);
            ssrcb[p] = src[e];
        }
        return;
    }

    const int bid = blockIdx.x - 128;             // 0..639
    const int tid = threadIdx.x;
    const int wave = tid >> 6;
    const int lane = tid & 63;
    const int lane16 = lane & 15;
    const int quad = lane >> 4;
    const int half = bid & 1;
    const int colbase = half * 128 + wave * 32;
    const int ntiles = (M + 31) >> 5;
    const int bstride = 320;                      // 640 GEMM blocks / 2 halves
    const int m   = tid >> 3;
    const int seg = (tid & 7) * 16;

    WIDE_B_PROLOGUE();

    int rt = bid >> 1;
    if (rt >= ntiles) return;

    float fa[16];
    load_a16(A, rt * 32 + m, M, seg, fa);
    split_store16(fa, &AhiB[0][0], &AloB[0][0], m, seg);
    __syncthreads();

    int cur_b = 0;
    while (true) {
        const int nrt = rt + bstride;
        float fn[16];
        if (nrt < ntiles) load_a16(A, nrt * 32 + m, M, seg, fn);

        const ushort* AH = &AhiB[cur_b][0];
        const ushort* AL = &AloB[cur_b][0];

        WIDE_MFMA_TILE();
        WIDE_STORE_TILE();

        if (nrt >= ntiles) break;
        split_store16(fn, &AhiB[cur_b ^ 1][0], &AloB[cur_b ^ 1][0], m, seg);
        __syncthreads();
        cur_b ^= 1;
        rt = nrt;
    }
}

// ---- L1: pre-split plane A (pure-copy staging) ----
__global__ __launch_bounds__(256, 3) void k_gemm_wide_pl(
    const ushort* __restrict__ Phi, const ushort* __restrict__ Plo,
    const ushort* __restrict__ Bth, const ushort* __restrict__ Btl,
    const float* __restrict__ bias,
    float* __restrict__ S, ushort* __restrict__ T, int M)
{
    __shared__ ushort AhiB[2][32 * APAD];
    __shared__ ushort AloB[2][32 * APAD];

    const int tid = threadIdx.x;
    const int wave = tid >> 6;
    const int lane = tid & 63;
    const int lane16 = lane & 15;
    const int quad = lane >> 4;
    const int half = blockIdx.x & 1;
    const int colbase = half * 128 + wave * 32;
    const int ntiles = (M + 31) >> 5;
    const int bstride = gridDim.x >> 1;
    const int m   = tid >> 3;
    const int seg = (tid & 7) * 16;

    WIDE_B_PROLOGUE();

    int rt = blockIdx.x >> 1;
    if (rt >= ntiles) return;

    uint4 ra[4];
    load_pl(Phi, Plo, rt * 32 + m, M, seg, ra);
    store_pl(ra, &AhiB[0][0], &AloB[0][0], m, seg);
    __syncthreads();

    int cur_b = 0;
    while (true) {
        const int nrt = rt + bstride;
        uint4 rn[4];
        if (nrt < ntiles) load_pl(Phi, Plo, nrt * 32 + m, M, seg, rn);

        const ushort* AH = &AhiB[cur_b][0];
        const ushort* AL = &AloB[cur_b][0];

        WIDE_MFMA_TILE();
        WIDE_STORE_TILE();

        if (nrt >= ntiles) break;
        store_pl(rn, &AhiB[cur_b ^ 1][0], &AloB[cur_b ^ 1][0], m, seg);
        __syncthreads();
        cur_b ^= 1;
        rt = nrt;
    }
}

// ---- L2 narrow: dout=40 dual (80 cols), plane A ----
__global__ __launch_bounds__(256, 2) void k_gemm_narrow_pl(
    const ushort* __restrict__ Phi, const ushort* __restrict__ Plo,
    const ushort* __restrict__ Bth, const ushort* __restrict__ Btl,
    const float* __restrict__ bias,
    float* __restrict__ S, ushort* __restrict__ T, int M)
{
    __shared__ ushort AhiB[2][32 * APAD];
    __shared__ ushort AloB[2][32 * APAD];

    const int tid = threadIdx.x;
    const int wave = tid >> 6;
    const int lane = tid & 63;
    const int lane16 = lane & 15;
    const int quad = lane >> 4;
    const int rtw = wave & 1;
    const int cg = wave >> 1;
    const int ctbase = cg * 3;
    const int nct = cg ? 2 : 3;
    const int ntiles = (M + 31) >> 5;
    const int m   = tid >> 3;
    const int seg = (tid & 7) * 16;

    bf16x8 Bh[4][3], Bl[4][3];
    #pragma unroll
    for (int c = 0; c < 4; ++c) {
        #pragma unroll
        for (int j = 0; j < 3; ++j) {
            if (j < nct) {
                const long boff = (long)(16 * (ctbase + j) + lane16) * KDIM + c * 32 + quad * 8;
                Bh[c][j] = *(const bf16x8*)(Bth + boff);
                Bl[c][j] = *(const bf16x8*)(Btl + boff);
            }
        }
    }

    int rt = blockIdx.x;
    if (rt >= ntiles) return;

    uint4 ra[4];
    load_pl(Phi, Plo, rt * 32 + m, M, seg, ra);
    store_pl(ra, &AhiB[0][0], &AloB[0][0], m, seg);
    __syncthreads();

    int cur_b = 0;
    while (true) {
        const int nrt = rt + gridDim.x;
        uint4 rn[4];
        if (nrt < ntiles) load_pl(Phi, Plo, nrt * 32 + m, M, seg, rn);

        const ushort* AH = &AhiB[cur_b][0];
        const ushort* AL = &AloB[cur_b][0];

        f32x4 acc[3] = {};
        #pragma unroll
        for (int c = 0; c < 4; ++c) {
            const int off = (rtw * 16 + lane16) * APAD + c * 32 + quad * 8;
            bf16x8 ah = *(const bf16x8*)&AH[off];
            bf16x8 al = *(const bf16x8*)&AL[off];
            #pragma unroll
            for (int j = 0; j < 3; ++j) {
                if (j < nct) {
                    acc[j] = __builtin_amdgcn_mfma_f32_16x16x32_bf16(Bh[c][j], ah, acc[j], 0, 0, 0);
                    acc[j] = __builtin_amdgcn_mfma_f32_16x16x32_bf16(Bl[c][j], ah, acc[j], 0, 0, 0);
                    acc[j] = __builtin_amdgcn_mfma_f32_16x16x32_bf16(Bh[c][j], al, acc[j], 0, 0, 0);
                }
            }
        }

        const int row = rt * 32 + rtw * 16 + lane16;
        #pragma unroll
        for (int j = 0; j < 3; ++j) {
            if (j < nct && row < M) {
                const int col0 = 16 * (ctbase + j) + quad * 4;
                if (col0 < 40) {
                    f32x4 bvv = *(const f32x4*)(bias + col0);
                    *(f32x4*)(S + (long)row * 40 + col0) = acc[j] + bvv;
                } else {
                    u16x4 t4;
                    #pragma unroll
                    for (int i = 0; i < 4; ++i) t4[i] = rne_bf16(acc[j][i]);
                    *(u16x4*)(T + (long)row * 40 + (col0 - 40)) = t4;
                }
            }
        }

        if (nrt >= ntiles) break;
        store_pl(rn, &AhiB[cur_b ^ 1][0], &AloB[cur_b ^ 1][0], m, seg);
        __syncthreads();
        cur_b ^= 1;
        rt = nrt;
    }
}

// =============== aggregation: wave-per-node, writes pre-split hi/lo planes ===============
__global__ __launch_bounds__(256) void k_agg128_pl(
    const float* __restrict__ S, const ushort* __restrict__ T,
    const int* __restrict__ off, const int* __restrict__ ssrcb,
    ushort* __restrict__ Phi, ushort* __restrict__ Plo, int nnodes)
{
    const int node = (blockIdx.x * 256 + threadIdx.x) >> 6;
    if (node >= nnodes) return;
    const int lane = threadIdx.x & 63;
    const int slot = lane >> 4;
    const int col8 = (lane & 15) * 8;

    const int a = off[node];
    const int b = off[node + 1];

    f32x4 acc0a = {0,0,0,0}, acc0b = {0,0,0,0};
    f32x4 acc1a = {0,0,0,0}, acc1b = {0,0,0,0};

    int i = a;
    for (; i + 8 <= b; i += 8) {
        int s0 = ssrcb[i + slot];
        int s1 = ssrcb[i + 4 + slot];
        u16x8 v0 = *(const u16x8*)(T + (long)s0 * 128 + col8);
        u16x8 v1 = *(const u16x8*)(T + (long)s1 * 128 + col8);
        #pragma unroll
        for (int j = 0; j < 4; ++j) {
            acc0a[j] += bf16_to_f32(v0[j]);
            acc0b[j] += bf16_to_f32(v0[4 + j]);
            acc1a[j] += bf16_to_f32(v1[j]);
            acc1b[j] += bf16_to_f32(v1[4 + j]);
        }
    }
    for (; i < b; i += 4) {
        int e = i + slot;
        if (e < b) {
            int s = ssrcb[e];
            u16x8 v = *(const u16x8*)(T + (long)s * 128 + col8);
            #pragma unroll
            for (int j = 0; j < 4; ++j) {
                acc0a[j] += bf16_to_f32(v[j]);
                acc0b[j] += bf16_to_f32(v[4 + j]);
            }
        }
    }
    f32x4 accA = acc0a + acc1a;
    f32x4 accB = acc0b + acc1b;

    #pragma unroll
    for (int mm = 16; mm <= 32; mm <<= 1) {
        #pragma unroll
        for (int j = 0; j < 4; ++j) {
            accA[j] += __shfl_xor((float)accA[j], mm);
            accB[j] += __shfl_xor((float)accB[j], mm);
        }
    }

    if (slot == 0) {
        int deg = b - a;
        float scale = (deg > 0) ? (1.0f / (float)deg) : 0.f;
        f32x4 sA = *(const f32x4*)(S + (long)node * 128 + col8);
        f32x4 sB = *(const f32x4*)(S + (long)node * 128 + col8 + 4);
        f32x4 rA = sA + accA * scale;
        f32x4 rB = sB + accB * scale;
        #pragma unroll
        for (int j = 0; j < 4; ++j) {
            rA[j] = fmaxf(rA[j], 0.f);   // relu (L0/L1 only use this kernel)
            rB[j] = fmaxf(rB[j], 0.f);
        }
        u16x8 ph, pl;
        #pragma unroll
        for (int j = 0; j < 4; ++j) {
            ushort h, l;
            split_bf16(rA[j], h, l); ph[j] = h; pl[j] = l;
        }
        #pragma unroll
        for (int j = 0; j < 4; ++j) {
            ushort h, l;
            split_bf16(rB[j], h, l); ph[4 + j] = h; pl[4 + j] = l;
        }
        *(u16x8*)(Phi + (long)node * 128 + col8) = ph;
        *(u16x8*)(Plo + (long)node * 128 + col8) = pl;
    }
}

__global__ __launch_bounds__(256) void k_agg40(
    const float* __restrict__ S, const ushort* __restrict__ T,
    const int* __restrict__ off, const int* __restrict__ ssrcb,
    float* __restrict__ out, int nnodes)
{
    const int node = (blockIdx.x * 256 + threadIdx.x) >> 6;
    if (node >= nnodes) return;
    const int lane = threadIdx.x & 63;
    const bool active = lane < 60;
    const int slot = active ? (lane / 10) : 5;
    const int fi = lane % 10;
    const int fo = fi * 4;

    const int a = off[node];
    const int b = off[node + 1];

    f32x4 acc0 = {0,0,0,0}, acc1 = {0,0,0,0};

    int i = a;
    for (; i + 12 <= b; i += 12) {
        int s0 = ssrcb[i + slot];
        int s1 = ssrcb[i + 6 + slot];
        u16x4 v0 = *(const u16x4*)(T + (long)s0 * 40 + fo);
        u16x4 v1 = *(const u16x4*)(T + (long)s1 * 40 + fo);
        if (active) {
            #pragma unroll
            for (int j = 0; j < 4; ++j) {
                acc0[j] += bf16_to_f32(v0[j]);
                acc1[j] += bf16_to_f32(v1[j]);
            }
        }
    }
    for (; i < b; i += 6) {
        int e = i + slot;
        if (active && e < b) {
            int s = ssrcb[e];
            u16x4 v = *(const u16x4*)(T + (long)s * 40 + fo);
            #pragma unroll
            for (int j = 0; j < 4; ++j) acc0[j] += bf16_to_f32(v[j]);
        }
    }
    f32x4 acc = acc0 + acc1;

    f32x4 tot = acc;
    #pragma unroll
    for (int d = 10; d <= 50; d += 10) {
        int srcl = fi + d;
        #pragma unroll
        for (int j = 0; j < 4; ++j) tot[j] += __shfl((float)acc[j], srcl);
    }

    if (lane < 10) {
        int deg = b - a;
        float scale = (deg > 0) ? (1.0f / (float)deg) : 0.f;
        f32x4 s4 = *(const f32x4*)(S + (long)node * 40 + fo);
        f32x4 r = s4 + tot * scale;
        *(f32x4*)(out + (long)node * 40 + fo) = r;
    }
}

// =============== launch ===============

extern "C" void kernel_launch(void* const* d_in, const int* in_sizes, int n_in,
                              void* d_out, int out_size, void* d_ws, size_t ws_size,
                              hipStream_t stream) {
    const float* feat = (const float*)d_in[0];
    const int*   src  = (const int*)d_in[1];
    const int*   dst  = (const int*)d_in[2];
    const float* ws0  = (const float*)d_in[3];
    const float* wn0  = (const float*)d_in[4];
    const float* b0   = (const float*)d_in[5];
    const float* ws1  = (const float*)d_in[6];
    const float* wn1  = (const float*)d_in[7];
    const float* b1   = (const float*)d_in[8];
    const float* ws2  = (const float*)d_in[9];
    const float* wn2  = (const float*)d_in[10];
    const float* b2   = (const float*)d_in[11];

    const int N = N_NODES;

    char* ws = (char*)d_ws;
    int*    offsets = (int*)(ws + 0);
    int*    cursor  = (int*)(ws + 200704);
    int*    degi    = (int*)(ws + 401408);
    int*    bsum    = (int*)(ws + 601600);
    int*    ssrcb   = (int*)(ws + 603648);
    ushort* Phi  = (ushort*)(ws + 3003904);   // 12.8 MB  (old hbuf region split in two)
    ushort* Plo  = (ushort*)(ws + 15803904);  // 12.8 MB
    float*  sbuf = (float*)(ws + 28603904);   // 25.6 MB fp32
    ushort* tbuf = (ushort*)(ws + 54203904);  // 12.8 MB bf16

    // B buffers live in d_out scratch (dead before agg40's final write;
    // convert must run before CSR's cursor/degi die, so can't overlap them)
    ushort* Ball = (ushort*)d_out;
    ushort* Bth0 = Ball;             // 128 cols dual: 256*128 ushorts
    ushort* Btl0 = Ball + 32768;
    ushort* Bth1 = Ball + 65536;
    ushort* Btl1 = Ball + 98304;
    ushort* Bth2 = Ball + 131072;    // 80*128 ushorts
    ushort* Btl2 = Ball + 141312;

    // ---- K0/K1: zero deg; count_deg || convert_w ----
    hipMemsetAsync(degi, 0, (size_t)N * sizeof(int), stream);
    k_prep<<<256, 256, 0, stream>>>(dst, degi, ws0, wn0, ws1, wn1, ws2, wn2,
                                    Bth0, Btl0, Bth1, Btl1, Bth2, Btl2);

    // ---- K2/K3: CSR offsets ----
    block_sums_kernel<<<NBLK, 256, 0, stream>>>(degi, bsum, N);
    scatter_fused_kernel<<<NBLK, 256, 0, stream>>>(degi, bsum, offsets, cursor, N, NBLK);

    const int ga = (N + 3) / 4;   // 12500 agg blocks

    // ---- layer 0: GEMM (fp32 feat) with fill_csr riding in blocks [0,128) ----
    k_gemm_wide_f32_fill<<<768, 256, 0, stream>>>(feat, Bth0, Btl0, b0, sbuf, tbuf, N,
                                                  src, dst, cursor, ssrcb);
    k_agg128_pl<<<ga, 256, 0, stream>>>(sbuf, tbuf, offsets, ssrcb, Phi, Plo, N);

    // ---- layer 1: GEMM from pre-split planes ----
    k_gemm_wide_pl<<<768, 256, 0, stream>>>(Phi, Plo, Bth1, Btl1, b1, sbuf, tbuf, N);
    k_agg128_pl<<<ga, 256, 0, stream>>>(sbuf, tbuf, offsets, ssrcb, Phi, Plo, N);

    // ---- layer 2: narrow GEMM from planes, agg writes final output ----
    k_gemm_narrow_pl<<<512, 256, 0, stream>>>(Phi, Plo, Bth2, Btl2, b2, sbuf, tbuf, N);
    k_agg40<<<ga, 256, 0, stream>>>(sbuf, tbuf, offsets, ssrcb, (float*)d_out, N);
}